// Round 8
// baseline (177.538 us; speedup 1.0000x reference)
//
#include <hip/hip_runtime.h>
#include <math.h>
#include <float.h>

// Problem constants (match reference)
constexpr int Bn  = 64;
constexpr int ICn = 2;
constexpr int OCn = 32;
constexpr int Kn  = 5;
constexpr int Ln  = 65536;
constexpr float FSc = 50000000.0f;
constexpr int JMAXn = 16;

// Conv tiling: block = (b, oc-group of 4, 16384-l chunk). 2048 blocks.
constexpr int TPB   = 256;
constexpr int CHUNK = 16384;             // l span per block
constexpr int NCH   = Ln / CHUNK;        // 4
constexpr int OCG   = 4;                 // oc per block
constexpr int NG    = OCn / OCG;         // 8 groups
constexpr int ITERS = CHUNK / (TPB * 4); // 16

typedef float f32x4 __attribute__((ext_vector_type(4)));

// ---------------------------------------------------------------------------
// Kernel 1: per-sample steerable weight generation (unchanged, negligible).
// ---------------------------------------------------------------------------
__global__ __launch_bounds__(64) void wgen_kernel(const int* __restrict__ z,
                                                  const float* __restrict__ s,
                                                  const float* __restrict__ w0,
                                                  float* __restrict__ w) {
    const int b  = blockIdx.x;
    const int oc = threadIdx.x;
    if (oc >= OCn) return;

    float pv[5];
#pragma unroll
    for (int c = 0; c < 5; ++c) {
        float v = s[b * 5 + c];
        if (isnan(v)) v = 0.0f;
        else if (isinf(v)) v = (v > 0.0f) ? FLT_MAX : -FLT_MAX;
        pv[c] = v;
    }
    const float neutral[5] = {0.0f, 1.0f, 1.0f, 0.0f, 0.0f};
#pragma unroll
    for (int c = 0; c < 5; ++c) {
        if (!(z[b * 5 + c] > 0)) pv[c] = neutral[c];
    }
    const float f0    = pv[0];
    const float alpha = pv[1];
    const float rho   = pv[2];
    const float a     = pv[4];

    float nw = rintf(5.0f / fmaxf(alpha, 0.001f));
    int new_W = (int)nw;
    if (new_W < 1) new_W = 1;
    if (new_W > JMAXn) new_W = JMAXn;
    const float nWf = (float)new_W;

    float M[Kn][Kn];
#pragma unroll
    for (int xi = 0; xi < Kn; ++xi)
#pragma unroll
        for (int y = 0; y < Kn; ++y) M[xi][y] = 0.0f;

#pragma unroll
    for (int xi = 0; xi < Kn; ++xi) {
        const float src2 = fmaxf((xi + 0.5f) * nWf / 5.0f - 0.5f, 0.0f);
        const int   j0   = (int)floorf(src2);
        const int   j1   = min(j0 + 1, new_W - 1);
        const float lam2 = src2 - (float)j0;
        const int   jj[2] = {j0, j1};
        const float cf[2] = {1.0f - lam2, lam2};
#pragma unroll
        for (int t = 0; t < 2; ++t) {
            const int   j  = jj[t];
            const float cc = cf[t];
            const float src1 = fmaxf((j + 0.5f) * 5.0f / nWf - 0.5f, 0.0f);
            const int   i0   = (int)floorf(src1);
            const int   i1   = min(i0 + 1, Kn - 1);
            const float lam1 = src1 - (float)i0;
#pragma unroll
            for (int y = 0; y < Kn; ++y) {
                const float e = ((y == i0) ? (1.0f - lam1) : 0.0f) +
                                ((y == i1) ? lam1 : 0.0f);
                M[xi][y] += cc * e;
            }
        }
    }

    const float* w0b = w0 + oc * (ICn * Kn);
    float wI[Kn], wQ[Kn];
#pragma unroll
    for (int xi = 0; xi < Kn; ++xi) {
        float aI = 0.0f, aQ = 0.0f;
#pragma unroll
        for (int y = 0; y < Kn; ++y) {
            aI += M[xi][y] * w0b[y];
            aQ += M[xi][y] * w0b[Kn + y];
        }
        wI[xi] = aI;
        wQ[xi] = aQ;
    }

    const float c2pi = (float)(2.0 * M_PI);
    const float cpi  = (float)M_PI;
#pragma unroll
    for (int n = 0; n < Kn; ++n) {
        const float nf  = (float)n;
        const float ph1 = ((c2pi * f0) * nf) / FSc;
        const float c1 = cosf(ph1), s1 = sinf(ph1);
        float I = wI[n], Q = wQ[n];
        float I2 = I * c1 - Q * s1;
        float Q2 = I * s1 + Q * c1;
        const float t   = nf / FSc;
        const float ph2 = (cpi * a) * (t * t);
        const float c2 = cosf(ph2), s2 = sinf(ph2);
        float I3 = I2 * c2 - Q2 * s2;
        float Q3 = I2 * s2 + Q2 * c2;
        wI[n] = rho * I3;
        wQ[n] = rho * Q3;
    }

    float* wb = w + (b * OCn + oc) * (ICn * Kn);
#pragma unroll
    for (int k = 0; k < Kn; ++k) {
        wb[k]      = wI[k];
        wb[Kn + k] = wQ[k];
    }
}

// ---------------------------------------------------------------------------
// Kernel 2: grouped conv1d. EXACT R6 structure (champion, 113.3 us) with ONE
// change: plain float4 stores instead of nontemporal. A/B: does routing the
// 537 MB write stream through L2/L3 (write-combining + MC scheduling slack,
// like fillBufferAligned's 6.7 TB/s) beat the nt direct-to-DRAM path?
// ---------------------------------------------------------------------------
__global__ __launch_bounds__(TPB) void conv_kernel(const float* __restrict__ x,
                                                   const float* __restrict__ w,
                                                   float* __restrict__ y) {
    const int blk   = blockIdx.x;
    const int chunk = blk & (NCH - 1);
    const int g     = (blk >> 2) & (NG - 1);
    const int b     = blk >> 5;
    const int oc0   = g * OCG;

    // 40 wave-uniform weights (scalar-cached): wv[j][i] for oc0+j
    const float* wbase = w + (size_t)(b * OCn + oc0) * (ICn * Kn);
    float wv[OCG][ICn * Kn];
#pragma unroll
    for (int j = 0; j < OCG; ++j)
#pragma unroll
        for (int i = 0; i < ICn * Kn; ++i) wv[j][i] = wbase[j * (ICn * Kn) + i];

    const float* x0 = x + (size_t)b * (ICn * Ln);
    const float* x1 = x0 + Ln;
    float* yg = y + ((size_t)(b * OCn + oc0)) * Ln + chunk * CHUNK;

    const int l0base = chunk * CHUNK + (int)threadIdx.x * 4;

#pragma unroll 2
    for (int it = 0; it < ITERS; ++it) {
        const int l0 = l0base + it * (TPB * 4);
        // window x[l0-4 .. l0+8): 12 floats per ic; used x[l0-2 .. l0+6)
        float xa[12], xc[12];
        if (l0 >= 4 && l0 + 8 <= Ln) {
#pragma unroll
            for (int q = 0; q < 3; ++q) {
                const float4 va = *reinterpret_cast<const float4*>(x0 + l0 - 4 + 4 * q);
                const float4 vb = *reinterpret_cast<const float4*>(x1 + l0 - 4 + 4 * q);
                xa[4 * q + 0] = va.x; xa[4 * q + 1] = va.y;
                xa[4 * q + 2] = va.z; xa[4 * q + 3] = va.w;
                xc[4 * q + 0] = vb.x; xc[4 * q + 1] = vb.y;
                xc[4 * q + 2] = vb.z; xc[4 * q + 3] = vb.w;
            }
        } else {
#pragma unroll
            for (int m = 0; m < 12; ++m) {
                const int gl = l0 - 4 + m;
                const bool ok = (gl >= 0 && gl < Ln);
                xa[m] = ok ? x0[gl] : 0.0f;
                xc[m] = ok ? x1[gl] : 0.0f;
            }
        }

        // 4 oc x 4 l accumulators from the shared window
        float acc[OCG][4];
#pragma unroll
        for (int j = 0; j < OCG; ++j) {
            float a0 = 0.0f, a1 = 0.0f, a2 = 0.0f, a3 = 0.0f;
#pragma unroll
            for (int k = 0; k < Kn; ++k) {
                const float wA = wv[j][k];        // ic = 0
                const float wB = wv[j][Kn + k];   // ic = 1
                a0 = fmaf(wA, xa[k + 2], a0); a0 = fmaf(wB, xc[k + 2], a0);
                a1 = fmaf(wA, xa[k + 3], a1); a1 = fmaf(wB, xc[k + 3], a1);
                a2 = fmaf(wA, xa[k + 4], a2); a2 = fmaf(wB, xc[k + 4], a2);
                a3 = fmaf(wA, xa[k + 5], a3); a3 = fmaf(wB, xc[k + 5], a3);
            }
            acc[j][0] = a0; acc[j][1] = a1; acc[j][2] = a2; acc[j][3] = a3;
        }

        // burst of 4 contiguous PLAIN stores (each: 64 lanes x 16 B = 1 KB run)
        const int off = it * (TPB * 4) + (int)threadIdx.x * 4;
#pragma unroll
        for (int j = 0; j < OCG; ++j) {
            f32x4 v = {acc[j][0], acc[j][1], acc[j][2], acc[j][3]};
            *reinterpret_cast<f32x4*>(yg + (size_t)j * Ln + off) = v;
        }
    }
}

extern "C" void kernel_launch(void* const* d_in, const int* in_sizes, int n_in,
                              void* d_out, int out_size, void* d_ws, size_t ws_size,
                              hipStream_t stream) {
    const float* x  = (const float*)d_in[0];   // (B, IC, 1, L) f32
    const int*   z  = (const int*)d_in[1];     // (B, 5) i32
    const float* s  = (const float*)d_in[2];   // (B, 5) f32
    const float* w0 = (const float*)d_in[3];   // (OC, IC, 1, K) f32
    float* y = (float*)d_out;                  // (B, OC, 1, L) f32
    float* w = (float*)d_ws;                   // B*OC*IC*K = 20480 floats (80 KB)

    hipLaunchKernelGGL(wgen_kernel, dim3(Bn), dim3(64), 0, stream, z, s, w0, w);
    hipLaunchKernelGGL(conv_kernel, dim3(Bn * NG * NCH), dim3(TPB), 0, stream, x, w, y);
}

// Round 9
// 116.463 us; speedup vs baseline: 1.5244x; 1.5244x over previous
//
#include <hip/hip_runtime.h>
#include <math.h>
#include <float.h>

// Problem constants (match reference)
constexpr int Bn  = 64;
constexpr int ICn = 2;
constexpr int OCn = 32;
constexpr int Kn  = 5;
constexpr int Ln  = 65536;
constexpr float FSc = 50000000.0f;
constexpr int JMAXn = 16;

// Conv tiling: block = (b, oc-group of 8, 8192-l chunk). 2048 blocks (same
// count as R6 champion; only OCG/CHUNK changed).
constexpr int TPB   = 256;
constexpr int CHUNK = 8192;              // l span per block
constexpr int NCH   = Ln / CHUNK;        // 8
constexpr int OCG   = 8;                 // oc per block
constexpr int NG    = OCn / OCG;         // 4 groups
constexpr int ITERS = CHUNK / (TPB * 4); // 8

typedef float f32x4 __attribute__((ext_vector_type(4)));

// ---------------------------------------------------------------------------
// Kernel 1: per-sample steerable weight generation (unchanged, negligible).
// ---------------------------------------------------------------------------
__global__ __launch_bounds__(64) void wgen_kernel(const int* __restrict__ z,
                                                  const float* __restrict__ s,
                                                  const float* __restrict__ w0,
                                                  float* __restrict__ w) {
    const int b  = blockIdx.x;
    const int oc = threadIdx.x;
    if (oc >= OCn) return;

    float pv[5];
#pragma unroll
    for (int c = 0; c < 5; ++c) {
        float v = s[b * 5 + c];
        if (isnan(v)) v = 0.0f;
        else if (isinf(v)) v = (v > 0.0f) ? FLT_MAX : -FLT_MAX;
        pv[c] = v;
    }
    const float neutral[5] = {0.0f, 1.0f, 1.0f, 0.0f, 0.0f};
#pragma unroll
    for (int c = 0; c < 5; ++c) {
        if (!(z[b * 5 + c] > 0)) pv[c] = neutral[c];
    }
    const float f0    = pv[0];
    const float alpha = pv[1];
    const float rho   = pv[2];
    const float a     = pv[4];

    float nw = rintf(5.0f / fmaxf(alpha, 0.001f));
    int new_W = (int)nw;
    if (new_W < 1) new_W = 1;
    if (new_W > JMAXn) new_W = JMAXn;
    const float nWf = (float)new_W;

    float M[Kn][Kn];
#pragma unroll
    for (int xi = 0; xi < Kn; ++xi)
#pragma unroll
        for (int y = 0; y < Kn; ++y) M[xi][y] = 0.0f;

#pragma unroll
    for (int xi = 0; xi < Kn; ++xi) {
        const float src2 = fmaxf((xi + 0.5f) * nWf / 5.0f - 0.5f, 0.0f);
        const int   j0   = (int)floorf(src2);
        const int   j1   = min(j0 + 1, new_W - 1);
        const float lam2 = src2 - (float)j0;
        const int   jj[2] = {j0, j1};
        const float cf[2] = {1.0f - lam2, lam2};
#pragma unroll
        for (int t = 0; t < 2; ++t) {
            const int   j  = jj[t];
            const float cc = cf[t];
            const float src1 = fmaxf((j + 0.5f) * 5.0f / nWf - 0.5f, 0.0f);
            const int   i0   = (int)floorf(src1);
            const int   i1   = min(i0 + 1, Kn - 1);
            const float lam1 = src1 - (float)i0;
#pragma unroll
            for (int y = 0; y < Kn; ++y) {
                const float e = ((y == i0) ? (1.0f - lam1) : 0.0f) +
                                ((y == i1) ? lam1 : 0.0f);
                M[xi][y] += cc * e;
            }
        }
    }

    const float* w0b = w0 + oc * (ICn * Kn);
    float wI[Kn], wQ[Kn];
#pragma unroll
    for (int xi = 0; xi < Kn; ++xi) {
        float aI = 0.0f, aQ = 0.0f;
#pragma unroll
        for (int y = 0; y < Kn; ++y) {
            aI += M[xi][y] * w0b[y];
            aQ += M[xi][y] * w0b[Kn + y];
        }
        wI[xi] = aI;
        wQ[xi] = aQ;
    }

    const float c2pi = (float)(2.0 * M_PI);
    const float cpi  = (float)M_PI;
#pragma unroll
    for (int n = 0; n < Kn; ++n) {
        const float nf  = (float)n;
        const float ph1 = ((c2pi * f0) * nf) / FSc;
        const float c1 = cosf(ph1), s1 = sinf(ph1);
        float I = wI[n], Q = wQ[n];
        float I2 = I * c1 - Q * s1;
        float Q2 = I * s1 + Q * c1;
        const float t   = nf / FSc;
        const float ph2 = (cpi * a) * (t * t);
        const float c2 = cosf(ph2), s2 = sinf(ph2);
        float I3 = I2 * c2 - Q2 * s2;
        float Q3 = I2 * s2 + Q2 * c2;
        wI[n] = rho * I3;
        wQ[n] = rho * Q3;
    }

    float* wb = w + (b * OCn + oc) * (ICn * Kn);
#pragma unroll
    for (int k = 0; k < Kn; ++k) {
        wb[k]      = wI[k];
        wb[Kn + k] = wQ[k];
    }
}

// ---------------------------------------------------------------------------
// Kernel 2: grouped conv1d. R6 structure with OCG=8 at UNCHANGED block count
// (2048): per x-window load-wait, a burst of 8 contiguous nt stores.
// Decouples R7's confound (OCG=8 bundled with 1024 blocks).
// ---------------------------------------------------------------------------
__global__ __launch_bounds__(TPB) void conv_kernel(const float* __restrict__ x,
                                                   const float* __restrict__ w,
                                                   float* __restrict__ y) {
    const int blk   = blockIdx.x;
    const int chunk = blk & (NCH - 1);
    const int g     = (blk >> 3) & (NG - 1);
    const int b     = blk >> 5;
    const int oc0   = g * OCG;

    // 80 block-uniform weights (SGPR-cached by compiler): wv[j][i] for oc0+j
    const float* wbase = w + (size_t)(b * OCn + oc0) * (ICn * Kn);
    float wv[OCG][ICn * Kn];
#pragma unroll
    for (int j = 0; j < OCG; ++j)
#pragma unroll
        for (int i = 0; i < ICn * Kn; ++i) wv[j][i] = wbase[j * (ICn * Kn) + i];

    const float* x0 = x + (size_t)b * (ICn * Ln);
    const float* x1 = x0 + Ln;
    float* yg = y + ((size_t)(b * OCn + oc0)) * Ln + chunk * CHUNK;

    const int l0base = chunk * CHUNK + (int)threadIdx.x * 4;

#pragma unroll 2
    for (int it = 0; it < ITERS; ++it) {
        const int l0 = l0base + it * (TPB * 4);
        // window x[l0-4 .. l0+8): 12 floats per ic; used x[l0-2 .. l0+6)
        float xa[12], xc[12];
        if (l0 >= 4 && l0 + 8 <= Ln) {
#pragma unroll
            for (int q = 0; q < 3; ++q) {
                const float4 va = *reinterpret_cast<const float4*>(x0 + l0 - 4 + 4 * q);
                const float4 vb = *reinterpret_cast<const float4*>(x1 + l0 - 4 + 4 * q);
                xa[4 * q + 0] = va.x; xa[4 * q + 1] = va.y;
                xa[4 * q + 2] = va.z; xa[4 * q + 3] = va.w;
                xc[4 * q + 0] = vb.x; xc[4 * q + 1] = vb.y;
                xc[4 * q + 2] = vb.z; xc[4 * q + 3] = vb.w;
            }
        } else {
#pragma unroll
            for (int m = 0; m < 12; ++m) {
                const int gl = l0 - 4 + m;
                const bool ok = (gl >= 0 && gl < Ln);
                xa[m] = ok ? x0[gl] : 0.0f;
                xc[m] = ok ? x1[gl] : 0.0f;
            }
        }

        // 8 oc x 4 l accumulators from the shared window
        float acc[OCG][4];
#pragma unroll
        for (int j = 0; j < OCG; ++j) {
            float a0 = 0.0f, a1 = 0.0f, a2 = 0.0f, a3 = 0.0f;
#pragma unroll
            for (int k = 0; k < Kn; ++k) {
                const float wA = wv[j][k];        // ic = 0
                const float wB = wv[j][Kn + k];   // ic = 1
                a0 = fmaf(wA, xa[k + 2], a0); a0 = fmaf(wB, xc[k + 2], a0);
                a1 = fmaf(wA, xa[k + 3], a1); a1 = fmaf(wB, xc[k + 3], a1);
                a2 = fmaf(wA, xa[k + 4], a2); a2 = fmaf(wB, xc[k + 4], a2);
                a3 = fmaf(wA, xa[k + 5], a3); a3 = fmaf(wB, xc[k + 5], a3);
            }
            acc[j][0] = a0; acc[j][1] = a1; acc[j][2] = a2; acc[j][3] = a3;
        }

        // burst of 8 contiguous nt stores (each: 64 lanes x 16 B = 1 KB run)
        const int off = it * (TPB * 4) + (int)threadIdx.x * 4;
#pragma unroll
        for (int j = 0; j < OCG; ++j) {
            f32x4 v = {acc[j][0], acc[j][1], acc[j][2], acc[j][3]};
            __builtin_nontemporal_store(
                v, reinterpret_cast<f32x4*>(yg + (size_t)j * Ln + off));
        }
    }
}

extern "C" void kernel_launch(void* const* d_in, const int* in_sizes, int n_in,
                              void* d_out, int out_size, void* d_ws, size_t ws_size,
                              hipStream_t stream) {
    const float* x  = (const float*)d_in[0];   // (B, IC, 1, L) f32
    const int*   z  = (const int*)d_in[1];     // (B, 5) i32
    const float* s  = (const float*)d_in[2];   // (B, 5) f32
    const float* w0 = (const float*)d_in[3];   // (OC, IC, 1, K) f32
    float* y = (float*)d_out;                  // (B, OC, 1, L) f32
    float* w = (float*)d_ws;                   // B*OC*IC*K = 20480 floats (80 KB)

    hipLaunchKernelGGL(wgen_kernel, dim3(Bn), dim3(64), 0, stream, z, s, w0, w);
    hipLaunchKernelGGL(conv_kernel, dim3(Bn * NG * NCH), dim3(TPB), 0, stream, x, w, y);
}

// Round 10
// 111.048 us; speedup vs baseline: 1.5987x; 1.0488x over previous
//
#include <hip/hip_runtime.h>
#include <math.h>
#include <float.h>

// Problem constants (match reference)
constexpr int Bn  = 64;
constexpr int ICn = 2;
constexpr int OCn = 32;
constexpr int Kn  = 5;
constexpr int Ln  = 65536;
constexpr float FSc = 50000000.0f;
constexpr int JMAXn = 16;

// Conv tiling: block = (b, oc-group of 4, 16384-l chunk). 2048 blocks.
// (R6 champion topology; this round adds register double-buffer pipelining.)
constexpr int TPB   = 256;
constexpr int CHUNK = 16384;             // l span per block
constexpr int NCH   = Ln / CHUNK;        // 4
constexpr int OCG   = 4;                 // oc per block
constexpr int NG    = OCn / OCG;         // 8 groups
constexpr int ITERS = CHUNK / (TPB * 4); // 16 (even)

typedef float f32x4 __attribute__((ext_vector_type(4)));

// ---------------------------------------------------------------------------
// Kernel 1: per-sample steerable weight generation (unchanged, negligible).
// ---------------------------------------------------------------------------
__global__ __launch_bounds__(64) void wgen_kernel(const int* __restrict__ z,
                                                  const float* __restrict__ s,
                                                  const float* __restrict__ w0,
                                                  float* __restrict__ w) {
    const int b  = blockIdx.x;
    const int oc = threadIdx.x;
    if (oc >= OCn) return;

    float pv[5];
#pragma unroll
    for (int c = 0; c < 5; ++c) {
        float v = s[b * 5 + c];
        if (isnan(v)) v = 0.0f;
        else if (isinf(v)) v = (v > 0.0f) ? FLT_MAX : -FLT_MAX;
        pv[c] = v;
    }
    const float neutral[5] = {0.0f, 1.0f, 1.0f, 0.0f, 0.0f};
#pragma unroll
    for (int c = 0; c < 5; ++c) {
        if (!(z[b * 5 + c] > 0)) pv[c] = neutral[c];
    }
    const float f0    = pv[0];
    const float alpha = pv[1];
    const float rho   = pv[2];
    const float a     = pv[4];

    float nw = rintf(5.0f / fmaxf(alpha, 0.001f));
    int new_W = (int)nw;
    if (new_W < 1) new_W = 1;
    if (new_W > JMAXn) new_W = JMAXn;
    const float nWf = (float)new_W;

    float M[Kn][Kn];
#pragma unroll
    for (int xi = 0; xi < Kn; ++xi)
#pragma unroll
        for (int y = 0; y < Kn; ++y) M[xi][y] = 0.0f;

#pragma unroll
    for (int xi = 0; xi < Kn; ++xi) {
        const float src2 = fmaxf((xi + 0.5f) * nWf / 5.0f - 0.5f, 0.0f);
        const int   j0   = (int)floorf(src2);
        const int   j1   = min(j0 + 1, new_W - 1);
        const float lam2 = src2 - (float)j0;
        const int   jj[2] = {j0, j1};
        const float cf[2] = {1.0f - lam2, lam2};
#pragma unroll
        for (int t = 0; t < 2; ++t) {
            const int   j  = jj[t];
            const float cc = cf[t];
            const float src1 = fmaxf((j + 0.5f) * 5.0f / nWf - 0.5f, 0.0f);
            const int   i0   = (int)floorf(src1);
            const int   i1   = min(i0 + 1, Kn - 1);
            const float lam1 = src1 - (float)i0;
#pragma unroll
            for (int y = 0; y < Kn; ++y) {
                const float e = ((y == i0) ? (1.0f - lam1) : 0.0f) +
                                ((y == i1) ? lam1 : 0.0f);
                M[xi][y] += cc * e;
            }
        }
    }

    const float* w0b = w0 + oc * (ICn * Kn);
    float wI[Kn], wQ[Kn];
#pragma unroll
    for (int xi = 0; xi < Kn; ++xi) {
        float aI = 0.0f, aQ = 0.0f;
#pragma unroll
        for (int y = 0; y < Kn; ++y) {
            aI += M[xi][y] * w0b[y];
            aQ += M[xi][y] * w0b[Kn + y];
        }
        wI[xi] = aI;
        wQ[xi] = aQ;
    }

    const float c2pi = (float)(2.0 * M_PI);
    const float cpi  = (float)M_PI;
#pragma unroll
    for (int n = 0; n < Kn; ++n) {
        const float nf  = (float)n;
        const float ph1 = ((c2pi * f0) * nf) / FSc;
        const float c1 = cosf(ph1), s1 = sinf(ph1);
        float I = wI[n], Q = wQ[n];
        float I2 = I * c1 - Q * s1;
        float Q2 = I * s1 + Q * c1;
        const float t   = nf / FSc;
        const float ph2 = (cpi * a) * (t * t);
        const float c2 = cosf(ph2), s2 = sinf(ph2);
        float I3 = I2 * c2 - Q2 * s2;
        float Q3 = I2 * s2 + Q2 * c2;
        wI[n] = rho * I3;
        wQ[n] = rho * Q3;
    }

    float* wb = w + (b * OCn + oc) * (ICn * Kn);
#pragma unroll
    for (int k = 0; k < Kn; ++k) {
        wb[k]      = wI[k];
        wb[Kn + k] = wQ[k];
    }
}

// --- helpers (force-inlined; all array indices compile-time) ---------------
__device__ __forceinline__ void fetch_win(const float* __restrict__ x0,
                                          const float* __restrict__ x1,
                                          int l0,
                                          float (&xa)[12], float (&xc)[12]) {
    if (l0 >= 4 && l0 + 8 <= Ln) {
#pragma unroll
        for (int q = 0; q < 3; ++q) {
            const float4 va = *reinterpret_cast<const float4*>(x0 + l0 - 4 + 4 * q);
            const float4 vb = *reinterpret_cast<const float4*>(x1 + l0 - 4 + 4 * q);
            xa[4 * q + 0] = va.x; xa[4 * q + 1] = va.y;
            xa[4 * q + 2] = va.z; xa[4 * q + 3] = va.w;
            xc[4 * q + 0] = vb.x; xc[4 * q + 1] = vb.y;
            xc[4 * q + 2] = vb.z; xc[4 * q + 3] = vb.w;
        }
    } else {
#pragma unroll
        for (int m = 0; m < 12; ++m) {
            const int gl = l0 - 4 + m;
            const bool ok = (gl >= 0 && gl < Ln);
            xa[m] = ok ? x0[gl] : 0.0f;
            xc[m] = ok ? x1[gl] : 0.0f;
        }
    }
}

__device__ __forceinline__ void compute_store(const float (&wv)[OCG][ICn * Kn],
                                              const float (&xa)[12],
                                              const float (&xc)[12],
                                              float* __restrict__ yg, int off) {
#pragma unroll
    for (int j = 0; j < OCG; ++j) {
        float a0 = 0.0f, a1 = 0.0f, a2 = 0.0f, a3 = 0.0f;
#pragma unroll
        for (int k = 0; k < Kn; ++k) {
            const float wA = wv[j][k];        // ic = 0
            const float wB = wv[j][Kn + k];   // ic = 1
            a0 = fmaf(wA, xa[k + 2], a0); a0 = fmaf(wB, xc[k + 2], a0);
            a1 = fmaf(wA, xa[k + 3], a1); a1 = fmaf(wB, xc[k + 3], a1);
            a2 = fmaf(wA, xa[k + 4], a2); a2 = fmaf(wB, xc[k + 4], a2);
            a3 = fmaf(wA, xa[k + 5], a3); a3 = fmaf(wB, xc[k + 5], a3);
        }
        f32x4 v = {a0, a1, a2, a3};
        __builtin_nontemporal_store(
            v, reinterpret_cast<f32x4*>(yg + (size_t)j * Ln + off));
    }
}

// ---------------------------------------------------------------------------
// Kernel 2: grouped conv1d, R6 champion topology + REGISTER DOUBLE-BUFFER:
// prefetch window(it+1) is issued BEFORE compute+store(it), so the
// dependent load-wait spans a full FMA+store block and nt stores stay in
// flight across it (load->use distance ~70 instrs instead of ~0).
// Even/odd unrolled buffers (no runtime-indexed register arrays).
// ---------------------------------------------------------------------------
__global__ __launch_bounds__(TPB) void conv_kernel(const float* __restrict__ x,
                                                   const float* __restrict__ w,
                                                   float* __restrict__ y) {
    const int blk   = blockIdx.x;
    const int chunk = blk & (NCH - 1);
    const int g     = (blk >> 2) & (NG - 1);
    const int b     = blk >> 5;
    const int oc0   = g * OCG;

    // 40 block-uniform weights: wv[j][i] for oc0+j
    const float* wbase = w + (size_t)(b * OCn + oc0) * (ICn * Kn);
    float wv[OCG][ICn * Kn];
#pragma unroll
    for (int j = 0; j < OCG; ++j)
#pragma unroll
        for (int i = 0; i < ICn * Kn; ++i) wv[j][i] = wbase[j * (ICn * Kn) + i];

    const float* x0 = x + (size_t)b * (ICn * Ln);
    const float* x1 = x0 + Ln;
    float* yg = y + ((size_t)(b * OCn + oc0)) * Ln + chunk * CHUNK;

    const int l0base  = chunk * CHUNK + (int)threadIdx.x * 4;
    const int offbase = (int)threadIdx.x * 4;

    float xaA[12], xcA[12], xaB[12], xcB[12];

    // prologue: fetch window 0 into A
    fetch_win(x0, x1, l0base, xaA, xcA);

#pragma unroll 2
    for (int itp = 0; itp < ITERS; itp += 2) {
        // even iter: prefetch it+1 into B, then compute/store from A
        fetch_win(x0, x1, l0base + (itp + 1) * (TPB * 4), xaB, xcB);
        compute_store(wv, xaA, xcA, yg, offbase + itp * (TPB * 4));

        // odd iter: prefetch it+2 into A (if any), compute/store from B
        if (itp + 2 < ITERS)
            fetch_win(x0, x1, l0base + (itp + 2) * (TPB * 4), xaA, xcA);
        compute_store(wv, xaB, xcB, yg, offbase + (itp + 1) * (TPB * 4));
    }
}

extern "C" void kernel_launch(void* const* d_in, const int* in_sizes, int n_in,
                              void* d_out, int out_size, void* d_ws, size_t ws_size,
                              hipStream_t stream) {
    const float* x  = (const float*)d_in[0];   // (B, IC, 1, L) f32
    const int*   z  = (const int*)d_in[1];     // (B, 5) i32
    const float* s  = (const float*)d_in[2];   // (B, 5) f32
    const float* w0 = (const float*)d_in[3];   // (OC, IC, 1, K) f32
    float* y = (float*)d_out;                  // (B, OC, 1, L) f32
    float* w = (float*)d_ws;                   // B*OC*IC*K = 20480 floats (80 KB)

    hipLaunchKernelGGL(wgen_kernel, dim3(Bn), dim3(64), 0, stream, z, s, w0, w);
    hipLaunchKernelGGL(conv_kernel, dim3(Bn * NG * NCH), dim3(TPB), 0, stream, x, w, y);
}

// Round 11
// 110.190 us; speedup vs baseline: 1.6112x; 1.0078x over previous
//
#include <hip/hip_runtime.h>
#include <math.h>
#include <float.h>

// Problem constants (match reference)
constexpr int Bn  = 64;
constexpr int ICn = 2;
constexpr int OCn = 32;
constexpr int Kn  = 5;
constexpr int Ln  = 65536;
constexpr float FSc = 50000000.0f;
constexpr int JMAXn = 16;

// Conv tiling: block = (b, oc-group of 4, 16384-l chunk). 2048 blocks.
// Single fused kernel: weights computed in-block (SGPR via readfirstlane).
constexpr int TPB   = 256;
constexpr int CHUNK = 16384;             // l span per block
constexpr int NCH   = Ln / CHUNK;        // 4
constexpr int OCG   = 4;                 // oc per block
constexpr int NG    = OCn / OCG;         // 8 groups
constexpr int ITERS = CHUNK / (TPB * 4); // 16 (even)

typedef float f32x4 __attribute__((ext_vector_type(4)));

__device__ __forceinline__ float uniformf(float v) {
    return __int_as_float(__builtin_amdgcn_readfirstlane(__float_as_int(v)));
}

// --- helpers (force-inlined; all array indices compile-time) ---------------
__device__ __forceinline__ void fetch_win(const float* __restrict__ x0,
                                          const float* __restrict__ x1,
                                          int l0,
                                          float (&xa)[12], float (&xc)[12]) {
    if (l0 >= 4 && l0 + 8 <= Ln) {
#pragma unroll
        for (int q = 0; q < 3; ++q) {
            const float4 va = *reinterpret_cast<const float4*>(x0 + l0 - 4 + 4 * q);
            const float4 vb = *reinterpret_cast<const float4*>(x1 + l0 - 4 + 4 * q);
            xa[4 * q + 0] = va.x; xa[4 * q + 1] = va.y;
            xa[4 * q + 2] = va.z; xa[4 * q + 3] = va.w;
            xc[4 * q + 0] = vb.x; xc[4 * q + 1] = vb.y;
            xc[4 * q + 2] = vb.z; xc[4 * q + 3] = vb.w;
        }
    } else {
#pragma unroll
        for (int m = 0; m < 12; ++m) {
            const int gl = l0 - 4 + m;
            const bool ok = (gl >= 0 && gl < Ln);
            xa[m] = ok ? x0[gl] : 0.0f;
            xc[m] = ok ? x1[gl] : 0.0f;
        }
    }
}

__device__ __forceinline__ void compute_store(const float (&wv)[OCG][ICn * Kn],
                                              const float (&xa)[12],
                                              const float (&xc)[12],
                                              float* __restrict__ yg, int off) {
#pragma unroll
    for (int j = 0; j < OCG; ++j) {
        float a0 = 0.0f, a1 = 0.0f, a2 = 0.0f, a3 = 0.0f;
#pragma unroll
        for (int k = 0; k < Kn; ++k) {
            const float wA = wv[j][k];        // ic = 0
            const float wB = wv[j][Kn + k];   // ic = 1
            a0 = fmaf(wA, xa[k + 2], a0); a0 = fmaf(wB, xc[k + 2], a0);
            a1 = fmaf(wA, xa[k + 3], a1); a1 = fmaf(wB, xc[k + 3], a1);
            a2 = fmaf(wA, xa[k + 4], a2); a2 = fmaf(wB, xc[k + 4], a2);
            a3 = fmaf(wA, xa[k + 5], a3); a3 = fmaf(wB, xc[k + 5], a3);
        }
        f32x4 v = {a0, a1, a2, a3};
        __builtin_nontemporal_store(
            v, reinterpret_cast<f32x4*>(yg + (size_t)j * Ln + off));
    }
}

// ---------------------------------------------------------------------------
// Fused kernel: weight generation (prologue, per-block, redundant across
// threads, results broadcast to SGPRs via readfirstlane) + R10 conv loop
// (register double-buffer, nt float4 store bursts, linear blk->y mapping).
// ---------------------------------------------------------------------------
__global__ __launch_bounds__(TPB) void conv_kernel(const float* __restrict__ x,
                                                   const int* __restrict__ z,
                                                   const float* __restrict__ s,
                                                   const float* __restrict__ w0,
                                                   float* __restrict__ y) {
    const int blk   = blockIdx.x;
    const int chunk = blk & (NCH - 1);
    const int g     = (blk >> 2) & (NG - 1);
    const int b     = blk >> 5;
    const int oc0   = g * OCG;

    // ===== weight generation for this block's (b, oc0..oc0+3) =====
    float pv[5];
#pragma unroll
    for (int c = 0; c < 5; ++c) {
        float v = s[b * 5 + c];
        if (isnan(v)) v = 0.0f;
        else if (isinf(v)) v = (v > 0.0f) ? FLT_MAX : -FLT_MAX;
        pv[c] = v;
    }
    const float neutral[5] = {0.0f, 1.0f, 1.0f, 0.0f, 0.0f};
#pragma unroll
    for (int c = 0; c < 5; ++c) {
        if (!(z[b * 5 + c] > 0)) pv[c] = neutral[c];
    }
    const float f0    = pv[0];
    const float alpha = pv[1];
    const float rho   = pv[2];
    const float a_chp = pv[4];

    float nw = rintf(5.0f / fmaxf(alpha, 0.001f));
    int new_W = (int)nw;
    if (new_W < 1) new_W = 1;
    if (new_W > JMAXn) new_W = JMAXn;
    const float nWf = (float)new_W;

    float M[Kn][Kn];
#pragma unroll
    for (int xi = 0; xi < Kn; ++xi)
#pragma unroll
        for (int yy = 0; yy < Kn; ++yy) M[xi][yy] = 0.0f;

#pragma unroll
    for (int xi = 0; xi < Kn; ++xi) {
        const float src2 = fmaxf((xi + 0.5f) * nWf / 5.0f - 0.5f, 0.0f);
        const int   j0   = (int)floorf(src2);
        const int   j1   = min(j0 + 1, new_W - 1);
        const float lam2 = src2 - (float)j0;
        const int   jj[2] = {j0, j1};
        const float cf[2] = {1.0f - lam2, lam2};
#pragma unroll
        for (int t = 0; t < 2; ++t) {
            const int   j  = jj[t];
            const float cc = cf[t];
            const float src1 = fmaxf((j + 0.5f) * 5.0f / nWf - 0.5f, 0.0f);
            const int   i0   = (int)floorf(src1);
            const int   i1   = min(i0 + 1, Kn - 1);
            const float lam1 = src1 - (float)i0;
#pragma unroll
            for (int yy = 0; yy < Kn; ++yy) {
                const float e = ((yy == i0) ? (1.0f - lam1) : 0.0f) +
                                ((yy == i1) ? lam1 : 0.0f);
                M[xi][yy] += cc * e;
            }
        }
    }

    const float c2pi = (float)(2.0 * M_PI);
    const float cpi  = (float)M_PI;

    float wv[OCG][ICn * Kn];   // broadcast to wave-uniform (SGPR) below
#pragma unroll
    for (int j = 0; j < OCG; ++j) {
        const int oc = oc0 + j;
        const float* w0b = w0 + oc * (ICn * Kn);
        float wI[Kn], wQ[Kn];
#pragma unroll
        for (int xi = 0; xi < Kn; ++xi) {
            float aI = 0.0f, aQ = 0.0f;
#pragma unroll
            for (int yy = 0; yy < Kn; ++yy) {
                aI += M[xi][yy] * w0b[yy];
                aQ += M[xi][yy] * w0b[Kn + yy];
            }
            wI[xi] = aI;
            wQ[xi] = aQ;
        }
#pragma unroll
        for (int n = 0; n < Kn; ++n) {
            const float nf  = (float)n;
            const float ph1 = ((c2pi * f0) * nf) / FSc;
            const float c1 = cosf(ph1), s1 = sinf(ph1);
            float I = wI[n], Q = wQ[n];
            float I2 = I * c1 - Q * s1;
            float Q2 = I * s1 + Q * c1;
            const float t   = nf / FSc;
            const float ph2 = (cpi * a_chp) * (t * t);
            const float c2 = cosf(ph2), s2 = sinf(ph2);
            float I3 = I2 * c2 - Q2 * s2;
            float Q3 = I2 * s2 + Q2 * c2;
            wv[j][n]      = uniformf(rho * I3);
            wv[j][Kn + n] = uniformf(rho * Q3);
        }
    }

    // ===== conv main loop (R10 structure) =====
    const float* x0 = x + (size_t)b * (ICn * Ln);
    const float* x1 = x0 + Ln;
    float* yg = y + ((size_t)(b * OCn + oc0)) * Ln + chunk * CHUNK;

    const int l0base  = chunk * CHUNK + (int)threadIdx.x * 4;
    const int offbase = (int)threadIdx.x * 4;

    float xaA[12], xcA[12], xaB[12], xcB[12];

    // prologue: fetch window 0 into A
    fetch_win(x0, x1, l0base, xaA, xcA);

#pragma unroll 2
    for (int itp = 0; itp < ITERS; itp += 2) {
        // even iter: prefetch it+1 into B, then compute/store from A
        fetch_win(x0, x1, l0base + (itp + 1) * (TPB * 4), xaB, xcB);
        compute_store(wv, xaA, xcA, yg, offbase + itp * (TPB * 4));

        // odd iter: prefetch it+2 into A (if any), compute/store from B
        if (itp + 2 < ITERS)
            fetch_win(x0, x1, l0base + (itp + 2) * (TPB * 4), xaA, xcA);
        compute_store(wv, xaB, xcB, yg, offbase + (itp + 1) * (TPB * 4));
    }
}

extern "C" void kernel_launch(void* const* d_in, const int* in_sizes, int n_in,
                              void* d_out, int out_size, void* d_ws, size_t ws_size,
                              hipStream_t stream) {
    const float* x  = (const float*)d_in[0];   // (B, IC, 1, L) f32
    const int*   z  = (const int*)d_in[1];     // (B, 5) i32
    const float* s  = (const float*)d_in[2];   // (B, 5) f32
    const float* w0 = (const float*)d_in[3];   // (OC, IC, 1, K) f32
    float* y = (float*)d_out;                  // (B, OC, 1, L) f32

    hipLaunchKernelGGL(conv_kernel, dim3(Bn * NG * NCH), dim3(TPB), 0, stream,
                       x, z, s, w0, y);
}

// Round 13
// 108.831 us; speedup vs baseline: 1.6313x; 1.0125x over previous
//
#include <hip/hip_runtime.h>
#include <math.h>
#include <float.h>

// Problem constants (match reference)
constexpr int Bn  = 64;
constexpr int ICn = 2;
constexpr int OCn = 32;
constexpr int Kn  = 5;
constexpr int Ln  = 65536;
constexpr float FSc = 50000000.0f;
constexpr int JMAXn = 16;

// Conv: sweeping-window topology with champion issue structure.
// 2048 blocks x 256 thr. Thread owns FIXED (b_off, oc-group of 4, l0);
// iterates 16 b-groups. Per iteration the chip writes one contiguous
// 32 MB window of y (4 full b-slices), like fillBufferAligned's sweep.
constexpr int TPB  = 256;
constexpr int OCG  = 4;                // oc per thread
constexpr int NG   = OCn / OCG;        // 8 oc-groups
constexpr int BG   = 4;                // b's per window
constexpr int NIT  = Bn / BG;          // 16 iterations
constexpr int NLT  = Ln / (TPB * 4);   // 64 l-tiles

typedef float f32x4 __attribute__((ext_vector_type(4)));

// ---------------------------------------------------------------------------
// Kernel 1: per-sample steerable weight generation (proven, negligible).
// ---------------------------------------------------------------------------
__global__ __launch_bounds__(64) void wgen_kernel(const int* __restrict__ z,
                                                  const float* __restrict__ s,
                                                  const float* __restrict__ w0,
                                                  float* __restrict__ w) {
    const int b  = blockIdx.x;
    const int oc = threadIdx.x;
    if (oc >= OCn) return;

    float pv[5];
#pragma unroll
    for (int c = 0; c < 5; ++c) {
        float v = s[b * 5 + c];
        if (isnan(v)) v = 0.0f;
        else if (isinf(v)) v = (v > 0.0f) ? FLT_MAX : -FLT_MAX;
        pv[c] = v;
    }
    const float neutral[5] = {0.0f, 1.0f, 1.0f, 0.0f, 0.0f};
#pragma unroll
    for (int c = 0; c < 5; ++c) {
        if (!(z[b * 5 + c] > 0)) pv[c] = neutral[c];
    }
    const float f0    = pv[0];
    const float alpha = pv[1];
    const float rho   = pv[2];
    const float a     = pv[4];

    float nw = rintf(5.0f / fmaxf(alpha, 0.001f));
    int new_W = (int)nw;
    if (new_W < 1) new_W = 1;
    if (new_W > JMAXn) new_W = JMAXn;
    const float nWf = (float)new_W;

    float M[Kn][Kn];
#pragma unroll
    for (int xi = 0; xi < Kn; ++xi)
#pragma unroll
        for (int y = 0; y < Kn; ++y) M[xi][y] = 0.0f;

#pragma unroll
    for (int xi = 0; xi < Kn; ++xi) {
        const float src2 = fmaxf((xi + 0.5f) * nWf / 5.0f - 0.5f, 0.0f);
        const int   j0   = (int)floorf(src2);
        const int   j1   = min(j0 + 1, new_W - 1);
        const float lam2 = src2 - (float)j0;
        const int   jj[2] = {j0, j1};
        const float cf[2] = {1.0f - lam2, lam2};
#pragma unroll
        for (int t = 0; t < 2; ++t) {
            const int   j  = jj[t];
            const float cc = cf[t];
            const float src1 = fmaxf((j + 0.5f) * 5.0f / nWf - 0.5f, 0.0f);
            const int   i0   = (int)floorf(src1);
            const int   i1   = min(i0 + 1, Kn - 1);
            const float lam1 = src1 - (float)i0;
#pragma unroll
            for (int y = 0; y < Kn; ++y) {
                const float e = ((y == i0) ? (1.0f - lam1) : 0.0f) +
                                ((y == i1) ? lam1 : 0.0f);
                M[xi][y] += cc * e;
            }
        }
    }

    const float* w0b = w0 + oc * (ICn * Kn);
    float wI[Kn], wQ[Kn];
#pragma unroll
    for (int xi = 0; xi < Kn; ++xi) {
        float aI = 0.0f, aQ = 0.0f;
#pragma unroll
        for (int y = 0; y < Kn; ++y) {
            aI += M[xi][y] * w0b[y];
            aQ += M[xi][y] * w0b[Kn + y];
        }
        wI[xi] = aI;
        wQ[xi] = aQ;
    }

    const float c2pi = (float)(2.0 * M_PI);
    const float cpi  = (float)M_PI;
#pragma unroll
    for (int n = 0; n < Kn; ++n) {
        const float nf  = (float)n;
        const float ph1 = ((c2pi * f0) * nf) / FSc;
        const float c1 = cosf(ph1), s1 = sinf(ph1);
        float I = wI[n], Q = wQ[n];
        float I2 = I * c1 - Q * s1;
        float Q2 = I * s1 + Q * c1;
        const float t   = nf / FSc;
        const float ph2 = (cpi * a) * (t * t);
        const float c2 = cosf(ph2), s2 = sinf(ph2);
        float I3 = I2 * c2 - Q2 * s2;
        float Q3 = I2 * s2 + Q2 * c2;
        wI[n] = rho * I3;
        wQ[n] = rho * Q3;
    }

    float* wb = w + (b * OCn + oc) * (ICn * Kn);
#pragma unroll
    for (int k = 0; k < Kn; ++k) {
        wb[k]      = wI[k];
        wb[Kn + k] = wQ[k];
    }
}

// --- helpers (force-inlined; all array indices compile-time) ---------------
__device__ __forceinline__ void fetch_win(const float* __restrict__ x0,
                                          const float* __restrict__ x1,
                                          int l0,
                                          float (&xa)[12], float (&xc)[12]) {
    if (l0 >= 4 && l0 + 8 <= Ln) {
#pragma unroll
        for (int q = 0; q < 3; ++q) {
            const float4 va = *reinterpret_cast<const float4*>(x0 + l0 - 4 + 4 * q);
            const float4 vb = *reinterpret_cast<const float4*>(x1 + l0 - 4 + 4 * q);
            xa[4 * q + 0] = va.x; xa[4 * q + 1] = va.y;
            xa[4 * q + 2] = va.z; xa[4 * q + 3] = va.w;
            xc[4 * q + 0] = vb.x; xc[4 * q + 1] = vb.y;
            xc[4 * q + 2] = vb.z; xc[4 * q + 3] = vb.w;
        }
    } else {
#pragma unroll
        for (int m = 0; m < 12; ++m) {
            const int gl = l0 - 4 + m;
            const bool ok = (gl >= 0 && gl < Ln);
            xa[m] = ok ? x0[gl] : 0.0f;
            xc[m] = ok ? x1[gl] : 0.0f;
        }
    }
}

__device__ __forceinline__ void compute_store(const float* __restrict__ wbase,
                                              const float (&xa)[12],
                                              const float (&xc)[12],
                                              float* __restrict__ yg, int l0) {
    // 40 block-uniform weights -> scalar loads
    float wv[OCG][ICn * Kn];
#pragma unroll
    for (int j = 0; j < OCG; ++j)
#pragma unroll
        for (int i = 0; i < ICn * Kn; ++i) wv[j][i] = wbase[j * (ICn * Kn) + i];

#pragma unroll
    for (int j = 0; j < OCG; ++j) {
        float a0 = 0.0f, a1 = 0.0f, a2 = 0.0f, a3 = 0.0f;
#pragma unroll
        for (int k = 0; k < Kn; ++k) {
            const float wA = wv[j][k];        // ic = 0
            const float wB = wv[j][Kn + k];   // ic = 1
            a0 = fmaf(wA, xa[k + 2], a0); a0 = fmaf(wB, xc[k + 2], a0);
            a1 = fmaf(wA, xa[k + 3], a1); a1 = fmaf(wB, xc[k + 3], a1);
            a2 = fmaf(wA, xa[k + 4], a2); a2 = fmaf(wB, xc[k + 4], a2);
            a3 = fmaf(wA, xa[k + 5], a3); a3 = fmaf(wB, xc[k + 5], a3);
        }
        f32x4 v = {a0, a1, a2, a3};
        __builtin_nontemporal_store(
            v, reinterpret_cast<f32x4*>(yg + (size_t)j * Ln + l0));
    }
}

// ---------------------------------------------------------------------------
// Kernel 2: grouped conv1d, sweeping-window order. Thread owns fixed
// (b_off, oc0, l0); iteration it handles b = it*BG + b_off. Chip-wide
// write set per iteration = 32 MB contiguous, sweeping linearly (fill
// topology) while keeping the champion per-iter issue structure
// (6 loads -> 40 FMA x4oc -> 4-store nt burst) + register double-buffer.
// Grid = BG(4) x NG(8) x NLT(64) = 2048 blocks  [R12 bug: was 8192 -> OOB].
// ---------------------------------------------------------------------------
__global__ __launch_bounds__(TPB) void conv_kernel(const float* __restrict__ x,
                                                   const float* __restrict__ w,
                                                   float* __restrict__ y) {
    const int blk   = blockIdx.x;          // [0, 2048)
    const int b_off = blk >> 9;            // 0..3   (512 blocks per b_off)
    const int rblk  = blk & 511;
    const int g     = rblk >> 6;           // 0..7   (64 blocks per group)
    const int pblk  = rblk & 63;           // 0..63
    const int oc0   = g * OCG;
    const int l0    = (pblk * TPB + (int)threadIdx.x) * 4;   // fixed per thread

    // per-iteration strides
    const size_t xstep = (size_t)BG * ICn * Ln;   // 4 b-slices of x
    const size_t wstep = (size_t)BG * OCn * ICn * Kn;
    const size_t ystep = (size_t)BG * OCn * Ln;   // 4 b-slices of y

    const float* xp = x + (size_t)b_off * (ICn * Ln);             // b = b_off
    const float* wp = w + (size_t)(b_off * OCn + oc0) * (ICn * Kn);
    float*       yp = y + (size_t)(b_off * OCn + oc0) * Ln;

    float xaA[12], xcA[12], xaB[12], xcB[12];

    // prologue: fetch window for it=0 into A
    fetch_win(xp, xp + Ln, l0, xaA, xcA);

#pragma unroll 2
    for (int itp = 0; itp < NIT; itp += 2) {
        // even iter: prefetch it+1 into B, compute/store it from A
        fetch_win(xp + xstep, xp + xstep + Ln, l0, xaB, xcB);
        compute_store(wp, xaA, xcA, yp, l0);
        xp += xstep; wp += wstep; yp += ystep;

        // odd iter: prefetch it+2 into A (if any), compute/store from B
        if (itp + 2 < NIT)
            fetch_win(xp + xstep, xp + xstep + Ln, l0, xaA, xcA);
        compute_store(wp, xaB, xcB, yp, l0);
        xp += xstep; wp += wstep; yp += ystep;
    }
}

extern "C" void kernel_launch(void* const* d_in, const int* in_sizes, int n_in,
                              void* d_out, int out_size, void* d_ws, size_t ws_size,
                              hipStream_t stream) {
    const float* x  = (const float*)d_in[0];   // (B, IC, 1, L) f32
    const int*   z  = (const int*)d_in[1];     // (B, 5) i32
    const float* s  = (const float*)d_in[2];   // (B, 5) f32
    const float* w0 = (const float*)d_in[3];   // (OC, IC, 1, K) f32
    float* y = (float*)d_out;                  // (B, OC, 1, L) f32
    float* w = (float*)d_ws;                   // B*OC*IC*K = 20480 floats (80 KB)

    hipLaunchKernelGGL(wgen_kernel, dim3(Bn), dim3(64), 0, stream, z, s, w0, w);
    hipLaunchKernelGGL(conv_kernel, dim3(BG * NG * NLT), dim3(TPB), 0, stream,
                       x, w, y);
}